// Round 1
// baseline (210.581 us; speedup 1.0000x reference)
//
#include <hip/hip_runtime.h>
#include <hip/hip_bf16.h>
#include <stdint.h>

// Problem: out[M=2048(size_out), N=8192(batch)] = W[K,M]^T @ X[N,K]^T
//   out[m,n] = sum_k W[k,m] * X[n,k]
#define M_DIM 2048
#define N_DIM 8192
#define K_DIM 2048

typedef _Float16 f16x8 __attribute__((ext_vector_type(8)));
typedef float    f32x4 __attribute__((ext_vector_type(4)));

// ---------------- conversion kernels ----------------

// X [N,K] fp32 -> Xb [N,K] f16 (elementwise, 8 elems/thread)
__global__ __launch_bounds__(256) void cvt_x_f16(const float* __restrict__ in,
                                                 _Float16* __restrict__ out) {
    size_t i = ((size_t)blockIdx.x * 256 + threadIdx.x) * 8;
    float4 a = *(const float4*)(in + i);
    float4 b = *(const float4*)(in + i + 4);
    f16x8 h;
    h[0] = (_Float16)a.x; h[1] = (_Float16)a.y; h[2] = (_Float16)a.z; h[3] = (_Float16)a.w;
    h[4] = (_Float16)b.x; h[5] = (_Float16)b.y; h[6] = (_Float16)b.z; h[7] = (_Float16)b.w;
    *(f16x8*)(out + i) = h;
}

// W [K,M] fp32 -> Wt [M,K] f16 (tiled transpose + convert)
__global__ __launch_bounds__(256) void transpose_w_f16(const float* __restrict__ W,
                                                       _Float16* __restrict__ Wt) {
    __shared__ float tile[32][33];
    const int tx = threadIdx.x & 31;
    const int ty = threadIdx.x >> 5;        // 0..7
    const int m0 = blockIdx.x * 32;
    const int k0 = blockIdx.y * 32;
#pragma unroll
    for (int i = 0; i < 32; i += 8)
        tile[ty + i][tx] = W[(size_t)(k0 + ty + i) * M_DIM + m0 + tx];
    __syncthreads();
#pragma unroll
    for (int i = 0; i < 32; i += 8)
        Wt[(size_t)(m0 + ty + i) * K_DIM + k0 + tx] = (_Float16)tile[tx][ty + i];
}

// ---------------- f16 MFMA GEMM (m97 structure) ----------------

__device__ __forceinline__ void load_to_lds16(const void* g, void* l) {
    __builtin_amdgcn_global_load_lds(
        (__attribute__((address_space(1))) void*)(uintptr_t)g,
        (__attribute__((address_space(3))) void*)l,
        16, 0, 0);
}

// A = Wt [M,K] f16 (K-contiguous), B = Xb [N,K] f16 (K-contiguous), C [M,N] fp32
__global__ __launch_bounds__(256, 3) void gemm_f16(const _Float16* __restrict__ A,
                                                   const _Float16* __restrict__ B,
                                                   float* __restrict__ C) {
    constexpr int BM = 128, BN = 128, BK = 32;
    __shared__ _Float16 As[BM * BK];   // [m][k] row-major, 8 KB
    __shared__ _Float16 Bs[BN * BK];   // [n][k] row-major, 8 KB

    const int tid  = threadIdx.x;
    const int wave = tid >> 6;
    const int lane = tid & 63;
    const int bm = blockIdx.x & 15;    // M_DIM/BM = 16
    const int bn = blockIdx.x >> 4;    // N_DIM/BN = 64
    const int wm = wave & 1;           // 2x2 wave grid, each wave 64x64
    const int wn = wave >> 1;
    const int lm = lane & 15;
    const int kq = lane >> 4;          // quad 0..3

    // staging: thread t loads 16B from row (t>>2), k-offset (t&3)*8 (f16 elems).
    // LDS dest = wave-uniform base + lane*16 (global_load_lds constraint) maps to
    // unpadded row-major [128][32] f16 exactly.
    const int srow = tid >> 2;
    const int scol = (tid & 3) * 8;
    const _Float16* ga = A + (size_t)(bm * BM + srow) * K_DIM + scol;
    const _Float16* gb = B + (size_t)(bn * BN + srow) * K_DIM + scol;
    char* la = (char*)As + wave * 1024;   // issue 0: rows [wave*16, +16); issue 1: +4096 -> rows+64
    char* lb = (char*)Bs + wave * 1024;

    // fragment read pointers: A[m=lane&15][k=kq*8+j]
    const _Float16* pa = As + (wm * 64 + lm) * BK + kq * 8;
    const _Float16* pb = Bs + (wn * 64 + lm) * BK + kq * 8;

    f32x4 acc[4][4] = {};

    for (int kt = 0; kt < K_DIM / BK; ++kt) {
        __syncthreads();                      // prev iter's LDS reads done
        load_to_lds16(ga,              la);
        load_to_lds16(ga + 64 * K_DIM, la + 4096);
        load_to_lds16(gb,              lb);
        load_to_lds16(gb + 64 * K_DIM, lb + 4096);
        ga += BK; gb += BK;
        __syncthreads();                      // drains vmcnt: staged data visible

        f16x8 af[4], bf[4];
#pragma unroll
        for (int i = 0; i < 4; ++i) af[i] = *(const f16x8*)(pa + i * 16 * BK);
#pragma unroll
        for (int i = 0; i < 4; ++i) bf[i] = *(const f16x8*)(pb + i * 16 * BK);
#pragma unroll
        for (int mi = 0; mi < 4; ++mi)
#pragma unroll
            for (int ni = 0; ni < 4; ++ni)
                acc[mi][ni] = __builtin_amdgcn_mfma_f32_16x16x32_f16(
                    af[mi], bf[ni], acc[mi][ni], 0, 0, 0);
    }

    // epilogue: D row (m) = (lane>>4)*4 + reg, col (n) = lane&15
    const int cm0 = bm * BM + wm * 64 + kq * 4;
    const int cn0 = bn * BN + wn * 64 + lm;
#pragma unroll
    for (int mi = 0; mi < 4; ++mi)
#pragma unroll
        for (int ni = 0; ni < 4; ++ni) {
            float* cp = C + (size_t)(cm0 + mi * 16) * N_DIM + cn0 + ni * 16;
#pragma unroll
            for (int r = 0; r < 4; ++r) cp[(size_t)r * N_DIM] = acc[mi][ni][r];
        }
}

// ---------------- fp32 fallback (only if ws too small) ----------------

__global__ __launch_bounds__(256) void gemm_f32_fallback(const float* __restrict__ X,
                                                         const float* __restrict__ W,
                                                         float* __restrict__ C) {
    // C[m][n] = sum_k W[k][m] * X[n][k];  64x64 tile, BK=16, 4x4 per thread
    __shared__ float As[16][64];  // As[k][m]
    __shared__ float Bs[16][64];  // Bs[k][n]
    const int tid = threadIdx.x;
    const int bm = blockIdx.x & 31;   // 2048/64
    const int bn = blockIdx.x >> 5;   // 8192/64
    const int tm = tid & 15, tn = tid >> 4;
    float c[4][4] = {};
    for (int k0 = 0; k0 < K_DIM; k0 += 16) {
        __syncthreads();
#pragma unroll
        for (int i = 0; i < 4; ++i) {
            int e = i * 256 + tid;
            As[e >> 6][e & 63] = W[(size_t)(k0 + (e >> 6)) * M_DIM + bm * 64 + (e & 63)];
        }
#pragma unroll
        for (int i = 0; i < 4; ++i) {
            int e = i * 256 + tid;
            Bs[e & 15][e >> 4] = X[(size_t)(bn * 64 + (e >> 4)) * K_DIM + k0 + (e & 15)];
        }
        __syncthreads();
#pragma unroll
        for (int kk = 0; kk < 16; ++kk)
#pragma unroll
            for (int i = 0; i < 4; ++i)
#pragma unroll
                for (int j = 0; j < 4; ++j)
                    c[i][j] += As[kk][tm * 4 + i] * Bs[kk][tn * 4 + j];
    }
#pragma unroll
    for (int i = 0; i < 4; ++i)
#pragma unroll
        for (int j = 0; j < 4; ++j)
            C[(size_t)(bm * 64 + tm * 4 + i) * N_DIM + bn * 64 + tn * 4 + j] = c[i][j];
}

// ---------------- launch ----------------

extern "C" void kernel_launch(void* const* d_in, const int* in_sizes, int n_in,
                              void* d_out, int out_size, void* d_ws, size_t ws_size,
                              hipStream_t stream) {
    const float* X = (const float*)d_in[0];  // [8192, 2048]
    const float* W = (const float*)d_in[1];  // [2048, 2048]
    // d_in[2] = bias: intentionally unused (reference discards it)
    float* C = (float*)d_out;                // [2048, 8192]

    const size_t xb_bytes = (size_t)N_DIM * K_DIM * sizeof(_Float16);  // 32 MB
    const size_t wt_bytes = (size_t)M_DIM * K_DIM * sizeof(_Float16);  //  8 MB

    if (ws_size >= xb_bytes + wt_bytes) {
        _Float16* Xb = (_Float16*)d_ws;
        _Float16* Wt = (_Float16*)((char*)d_ws + xb_bytes);
        cvt_x_f16<<<(N_DIM * K_DIM) / (256 * 8), 256, 0, stream>>>(X, Xb);
        transpose_w_f16<<<dim3(M_DIM / 32, K_DIM / 32), 256, 0, stream>>>(W, Wt);
        gemm_f16<<<(M_DIM / 128) * (N_DIM / 128), 256, 0, stream>>>(Wt, Xb, C);
    } else {
        gemm_f32_fallback<<<(M_DIM / 64) * (N_DIM / 64), 256, 0, stream>>>(X, W, C);
    }
}

// Round 2
// 193.466 us; speedup vs baseline: 1.0885x; 1.0885x over previous
//
#include <hip/hip_runtime.h>
#include <stdint.h>

// Problem: out[M=2048(size_out), N=8192(batch)] = W[K,M]^T @ X[N,K]^T
//   out[m,n] = sum_k W[k,m] * X[n,k]
#define M_DIM 2048
#define N_DIM 8192
#define K_DIM 2048

typedef _Float16 f16x8 __attribute__((ext_vector_type(8)));
typedef _Float16 f16x4 __attribute__((ext_vector_type(4)));
typedef float    f32x4 __attribute__((ext_vector_type(4)));

// ---------------- fused prep: cvt X (blocks 0..8191) + transpose W (8192..12287) ----------------

__global__ __launch_bounds__(256) void prep(const float* __restrict__ X,
                                            const float* __restrict__ W,
                                            _Float16* __restrict__ Xb,
                                            _Float16* __restrict__ Wt) {
    __shared__ float tile[32][33];
    int b = blockIdx.x;
    if (b < 8192) {
        // X [N,K] fp32 -> Xb [N,K] f16, 8 elems/thread
        size_t i = ((size_t)b * 256 + threadIdx.x) * 8;
        float4 a = *(const float4*)(X + i);
        float4 c = *(const float4*)(X + i + 4);
        f16x8 h;
        h[0] = (_Float16)a.x; h[1] = (_Float16)a.y; h[2] = (_Float16)a.z; h[3] = (_Float16)a.w;
        h[4] = (_Float16)c.x; h[5] = (_Float16)c.y; h[6] = (_Float16)c.z; h[7] = (_Float16)c.w;
        *(f16x8*)(Xb + i) = h;
    } else {
        // W [K,M] fp32 -> Wt [M,K] f16, 32x32 tile
        b -= 8192;                         // 4096 blocks
        const int m0 = (b & 63) * 32;
        const int k0 = (b >> 6) * 32;
        const int tx = threadIdx.x & 31;
        const int ty = threadIdx.x >> 5;   // 0..7
#pragma unroll
        for (int i = 0; i < 32; i += 8)
            tile[ty + i][tx] = W[(size_t)(k0 + ty + i) * M_DIM + m0 + tx];  // tile[k][m]
        __syncthreads();
        const int ml = threadIdx.x >> 3;        // 0..31
        const int kg = (threadIdx.x & 7) * 4;   // 0..28
        f16x4 v;
#pragma unroll
        for (int j = 0; j < 4; ++j) v[j] = (_Float16)tile[kg + j][ml];
        *(f16x4*)(Wt + (size_t)(m0 + ml) * K_DIM + k0 + kg) = v;            // 8B store
    }
}

// ---------------- f16 MFMA GEMM: 128x128 tile, BK=64, XOR-swizzled LDS ----------------

__device__ __forceinline__ void load_to_lds16(const void* g, void* l) {
    __builtin_amdgcn_global_load_lds(
        (__attribute__((address_space(1))) void*)(uintptr_t)g,
        (__attribute__((address_space(3))) void*)l,
        16, 0, 0);
}

// A = Wt [M,K] f16 (K-contiguous), B = Xb [N,K] f16 (K-contiguous), C [M,N] fp32
//
// LDS tile: [row r][chunk c] of 16B chunks, 8 chunks/row (BK=64 f16 = 128B row).
// Swizzle: LDS slot (r, c) holds global chunk (r, c ^ (r&7)).
//  - staging: global_load_lds lane l writes LDS chunk (w*64 + i*256 + l); its
//    r = i*32 + w*8 + (l>>3), c = l&7 -> global k-chunk = (l&7) ^ (l>>3).
//  - frag reads: row r, global chunk (h*4+kq) lives at c = (h*4+kq) ^ (r&7);
//    r&7 == lm&7 (row offsets i*16, wm*64 are 0 mod 8). 16 lanes of a quad then
//    cover each 4-bank group exactly twice -> conflict-free (2-way is free, m136).
__global__ __launch_bounds__(256, 4) void gemm_f16(const _Float16* __restrict__ A,
                                                   const _Float16* __restrict__ B,
                                                   float* __restrict__ C) {
    constexpr int BK = 64;
    __shared__ _Float16 As[128 * BK];   // 16 KB
    __shared__ _Float16 Bs[128 * BK];   // 16 KB

    const int tid  = threadIdx.x;
    const int wave = tid >> 6;
    const int lane = tid & 63;

    // XCD swizzle: consecutive-bn groups per XCD for B-tile L2 locality
    const int bid = ((blockIdx.x & 7) << 7) | (blockIdx.x >> 3);
    const int bm = bid & 15;           // M_DIM/128 = 16
    const int bn = bid >> 4;           // N_DIM/128 = 64
    const int wm = wave & 1;           // 2x2 wave grid, each wave 64x64
    const int wn = wave >> 1;
    const int lm = lane & 15;
    const int kq = lane >> 4;          // 0..3

    // staging: issue i covers rows i*32 + wave*8 + (lane>>3), chunk col lane&7
    const int srow = (wave << 3) + (lane >> 3);
    const int scol = ((lane & 7) ^ (lane >> 3)) * 8;      // swizzled global k offset
    const _Float16* ga = A + (size_t)(bm * 128 + srow) * K_DIM + scol;
    const _Float16* gb = B + (size_t)(bn * 128 + srow) * K_DIM + scol;
    char* la = (char*)As + wave * 1024;                   // + issue*4096
    char* lb = (char*)Bs + wave * 1024;

    // fragment addressing
    const int ar = wm * 64 + lm;       // af[i] row = ar + i*16
    const int br = wn * 64 + lm;
    const int xr = lm & 7;

    f32x4 acc[4][4] = {};

    for (int kt = 0; kt < K_DIM / BK; ++kt) {
        __syncthreads();               // prev iter's LDS reads done
#pragma unroll
        for (int i = 0; i < 4; ++i) {
            load_to_lds16(ga + (size_t)(i * 32) * K_DIM, la + i * 4096);
            load_to_lds16(gb + (size_t)(i * 32) * K_DIM, lb + i * 4096);
        }
        ga += BK; gb += BK;
        __syncthreads();               // vmcnt drained: staged data visible

#pragma unroll
        for (int h = 0; h < 2; ++h) {
            const int ca = (((h << 2) + kq) ^ xr) * 8;    // swizzled chunk, elems
            f16x8 af[4], bf[4];
#pragma unroll
            for (int i = 0; i < 4; ++i) af[i] = *(const f16x8*)(As + (ar + i * 16) * BK + ca);
#pragma unroll
            for (int i = 0; i < 4; ++i) bf[i] = *(const f16x8*)(Bs + (br + i * 16) * BK + ca);
#pragma unroll
            for (int mi = 0; mi < 4; ++mi)
#pragma unroll
                for (int ni = 0; ni < 4; ++ni)
                    acc[mi][ni] = __builtin_amdgcn_mfma_f32_16x16x32_f16(
                        af[mi], bf[ni], acc[mi][ni], 0, 0, 0);
        }
    }

    // epilogue: D row (m) = kq*4 + reg, col (n) = lm
    const int cm0 = bm * 128 + wm * 64 + kq * 4;
    const int cn0 = bn * 128 + wn * 64 + lm;
#pragma unroll
    for (int mi = 0; mi < 4; ++mi)
#pragma unroll
        for (int ni = 0; ni < 4; ++ni) {
            float* cp = C + (size_t)(cm0 + mi * 16) * N_DIM + cn0 + ni * 16;
#pragma unroll
            for (int r = 0; r < 4; ++r) cp[(size_t)r * N_DIM] = acc[mi][ni][r];
        }
}

// ---------------- fp32 fallback (only if ws too small) ----------------

__global__ __launch_bounds__(256) void gemm_f32_fallback(const float* __restrict__ X,
                                                         const float* __restrict__ W,
                                                         float* __restrict__ C) {
    __shared__ float As2[16][64];  // As2[k][m]
    __shared__ float Bs2[16][64];  // Bs2[k][n]
    const int tid = threadIdx.x;
    const int bm = blockIdx.x & 31;
    const int bn = blockIdx.x >> 5;
    const int tm = tid & 15, tn = tid >> 4;
    float c[4][4] = {};
    for (int k0 = 0; k0 < K_DIM; k0 += 16) {
        __syncthreads();
#pragma unroll
        for (int i = 0; i < 4; ++i) {
            int e = i * 256 + tid;
            As2[e >> 6][e & 63] = W[(size_t)(k0 + (e >> 6)) * M_DIM + bm * 64 + (e & 63)];
        }
#pragma unroll
        for (int i = 0; i < 4; ++i) {
            int e = i * 256 + tid;
            Bs2[e & 15][e >> 4] = X[(size_t)(bn * 64 + (e >> 4)) * K_DIM + k0 + (e & 15)];
        }
        __syncthreads();
#pragma unroll
        for (int kk = 0; kk < 16; ++kk)
#pragma unroll
            for (int i = 0; i < 4; ++i)
#pragma unroll
                for (int j = 0; j < 4; ++j)
                    c[i][j] += As2[kk][tm * 4 + i] * Bs2[kk][tn * 4 + j];
    }
#pragma unroll
    for (int i = 0; i < 4; ++i)
#pragma unroll
        for (int j = 0; j < 4; ++j)
            C[(size_t)(bm * 64 + tm * 4 + i) * N_DIM + bn * 64 + tn * 4 + j] = c[i][j];
}

// ---------------- launch ----------------

extern "C" void kernel_launch(void* const* d_in, const int* in_sizes, int n_in,
                              void* d_out, int out_size, void* d_ws, size_t ws_size,
                              hipStream_t stream) {
    const float* X = (const float*)d_in[0];  // [8192, 2048]
    const float* W = (const float*)d_in[1];  // [2048, 2048]
    // d_in[2] = bias: intentionally unused (reference discards it)
    float* C = (float*)d_out;                // [2048, 8192]

    const size_t xb_bytes = (size_t)N_DIM * K_DIM * sizeof(_Float16);  // 32 MB
    const size_t wt_bytes = (size_t)M_DIM * K_DIM * sizeof(_Float16);  //  8 MB

    if (ws_size >= xb_bytes + wt_bytes) {
        _Float16* Xb = (_Float16*)d_ws;
        _Float16* Wt = (_Float16*)((char*)d_ws + xb_bytes);
        prep<<<8192 + 4096, 256, 0, stream>>>(X, W, Xb, Wt);
        gemm_f16<<<(M_DIM / 128) * (N_DIM / 128), 256, 0, stream>>>(Wt, Xb, C);
    } else {
        gemm_f32_fallback<<<(M_DIM / 64) * (N_DIM / 64), 256, 0, stream>>>(X, W, C);
    }
}